// Round 9
// baseline (401.067 us; speedup 1.0000x reference)
//
#include <hip/hip_runtime.h>
#include <math.h>

// ---------------------------------------------------------------------------
// Round 8: 4-way h-split, 128 blocks x 1024 threads, k-history in LDS.
//  - rg = bid&31 owns 16 rows; sub = bid>>5 (0..3) owns h in [64*sub,64*sub+64)
//    (= 192 gate cols = 12 n-tiles; waves 0..11 one tile each, B hi+lo in
//    64 VGPRs loaded once).
//  - Wave w == row w. Thread owns 4 A-elements (row w, h0=lane*4): polls 4
//    packets from ONE producer; publishes 1 packet (index base+t, coalesced).
//    Poll traffic halves vs round 6; skew max over 4 producers (was 8).
//  - Sleep-first polls (round 7 post-mortem: hot-spin floods the fabric).
//  - MFMA chain order/operands bitwise identical to round 6 -> identical g,
//    k, trajectory. Err-partial tree reshape (double ~1e-16) inert.
//  - k-history lives in LDS (thread-private slots; same-thread ds order only).
//
// ws layout (bytes):
//   [0,393216)        Wb_hi  ushort[196608] B-frag-packed bf16 hi Wih[:,:256]
//   [393216,786432)   Wb_lo  ushort[196608] bf16 lo
//   [786432,917504)   Wpt    float[32768]
//   [917504,983040)   Wlt    float[16384]
//   [1048576,3145728) kpk    u64[2][32][4][16][64]  k packets (seq|bits)
//   [3145728,3149824) ppk    u64[2][32][4][2]       err-partial packets
// Dynamic LDS (byte offsets):
//   [0,16384)       A-frags hi/lo, XOR-swizzled (alias: x-staging, y-staging)
//   [16384,28928)   g_lds[16][196] floats (cols 0..63 r, 64..127 z, 128..191 n)
//   [28928,143616)  k_lds[7][16][256] floats (thread-private slots)
//   [143616,143744) red double[16] | [143744,143752) s_b double
// ---------------------------------------------------------------------------

typedef __attribute__((ext_vector_type(8))) short bf16x8s;
typedef __attribute__((ext_vector_type(4))) float f32x4;

#define F(x) ((float)(x))
#define GOFF 4096    // floats
#define KOFF 7232    // floats
#define REDF 35904   // floats (16 doubles)
#define SBF 35936    // floats (1 double)
// byte-offset XOR swizzle within each 8KB A-frag region (write & read sides)
#define SWZ(b) ((b) ^ ((((b) >> 8) & 7) << 4))

static __device__ __forceinline__ unsigned short f2bf(float f) {
  unsigned u = __float_as_uint(f);
  unsigned r = (u + 0x7FFFu + ((u >> 16) & 1u)) >> 16;
  return (unsigned short)r;
}
static __device__ __forceinline__ float bf2f(unsigned short b) {
  return __uint_as_float(((unsigned)b) << 16);
}
static __device__ __forceinline__ float sigm(float x) {
  return 1.0f / (1.0f + __expf(-x));
}
static __device__ __forceinline__ float tanh_fast(float x) {
  float e = __expf(-2.0f * fabsf(x));
  float t = (1.0f - e) / (1.0f + e);
  return copysignf(t, x);
}
static __device__ __forceinline__ void pub64(unsigned long long* p,
                                             unsigned long long v) {
  __hip_atomic_store(p, v, __ATOMIC_RELAXED, __HIP_MEMORY_SCOPE_AGENT);
}
static __device__ __forceinline__ unsigned long long ld64(
    const unsigned long long* p) {
  return __hip_atomic_load(p, __ATOMIC_RELAXED, __HIP_MEMORY_SCOPE_AGENT);
}

__global__ void prep_kernel(const float* __restrict__ Wih,
                            const float* __restrict__ Wp,
                            const float* __restrict__ Wl,
                            float* __restrict__ ws) {
  int i = blockIdx.x * blockDim.x + threadIdx.x;
  if (i < 196608) {
    const int j = i & 7, l = (i >> 3) & 63, ks = (i >> 9) & 7, nt = i >> 12;
    const int c = nt * 16 + (l & 15);          // gate-output column
    const int k = ks * 32 + (l >> 4) * 8 + j;  // k index (same perm as A)
    const float f = Wih[c * 257 + k];
    unsigned short hi = f2bf(f);
    unsigned short lo = f2bf(f - bf2f(hi));
    ((unsigned short*)ws)[i] = hi;
    ((unsigned short*)ws)[196608 + i] = lo;
  } else if (i < 229376) {
    int ii = i - 196608; int hh = ii & 255, k = ii >> 8;
    ws[i] = Wp[hh * 128 + k];
  } else if (i < 245760) {
    int ii = i - 229376; int c = ii & 63, k = ii >> 6;
    ws[i] = Wl[c * 256 + k];
  }
}

// Front half of one f-eval: pack -> MFMA -> nonlin -> publish 1 k packet.
// Returns this thread's slice-k value (row=t>>6, hl=t&63) in ks_out.
__device__ __forceinline__ void eval_front(
    float* __restrict__ smem, unsigned long long* __restrict__ kpk,
    const bf16x8s (&bhr)[8], const bf16x8s (&blr)[8],
    int rg, int sub, int lane, int w, int fo, int t, int ec,
    const float (&ys)[4], float ts_,
    float cr0, float cz0, float bn_, float wtr, float wtz, float wtn,
    float bhn, float& ks_out) {
  // ---- pack ys -> A-frags (bf16 hi/lo), swizzled locations ----
  unsigned short h_[4], l_[4];
#pragma unroll
  for (int c = 0; c < 4; ++c) {
    h_[c] = f2bf(ys[c]);
    l_[c] = f2bf(ys[c] - bf2f(h_[c]));
  }
  char* yB = (char*)smem;
  *(ushort4*)(yB + SWZ(2 * fo)) = make_ushort4(h_[0], h_[1], h_[2], h_[3]);
  *(ushort4*)(yB + 8192 + SWZ(2 * fo)) = make_ushort4(l_[0], l_[1], l_[2], l_[3]);
  __syncthreads();

  // ---- MFMA: waves 0..11, B in registers, single-acc chain (== round 6) ----
  if (w < 12) {
    f32x4 ac = {0.f, 0.f, 0.f, 0.f};
#pragma unroll
    for (int ks2 = 0; ks2 < 8; ++ks2) {
      const int rb = SWZ(16 * (ks2 * 64 + lane));
      const bf16x8s ah = *(const bf16x8s*)(yB + rb);
      const bf16x8s al = *(const bf16x8s*)(yB + 8192 + rb);
      ac = __builtin_amdgcn_mfma_f32_16x16x32_bf16(al, bhr[ks2], ac, 0, 0, 0);
      ac = __builtin_amdgcn_mfma_f32_16x16x32_bf16(ah, blr[ks2], ac, 0, 0, 0);
      ac = __builtin_amdgcn_mfma_f32_16x16x32_bf16(ah, bhr[ks2], ac, 0, 0, 0);
    }
    // C: col=lane&15, row=(lane>>4)*4+j -> g_lds[row][gcol] (stride 196)
    const int gcol = (w >> 2) * 64 + (w & 3) * 16 + (lane & 15);
    const int gr0 = (lane >> 4) * 4;
#pragma unroll
    for (int j = 0; j < 4; ++j) smem[GOFF + (gr0 + j) * 196 + gcol] = ac[j];
  }
  __syncthreads();

  // ---- GRU nonlinearity for (row=t>>6, hl=t&63); publish packet ----
  {
    const int row = t >> 6, hl = t & 63;
    const float gR = smem[GOFF + row * 196 + hl];
    const float gZ = smem[GOFF + row * 196 + 64 + hl];
    const float gN = smem[GOFF + row * 196 + 128 + hl];
    const float rv = sigm(gR + cr0 + ts_ * wtr);
    const float zv = sigm(gZ + cz0 + ts_ * wtz);
    const float nv = tanh_fast(gN + bn_ + ts_ * wtn + rv * bhn);
    const float kv = (1.0f - zv) * nv;
    ks_out = kv;
    pub64(kpk + ((size_t)((ec & 1) * 128 + rg * 4 + sub)) * 1024 + t,
          ((unsigned long long)(unsigned)(ec + 1) << 32) | __float_as_uint(kv));
  }
}

// Poll own 4 k packets (row=w, h0..h0+3, single producer); write k_lds[slot].
__device__ __forceinline__ void eval_poll(
    float* __restrict__ smem, const unsigned long long* __restrict__ kpk,
    int rg, int w, int lane, int h0, int ec, int slot) {
  const unsigned long long* kb =
      kpk + ((size_t)((ec & 1) * 128 + rg * 4 + (lane >> 4))) * 1024 +
      w * 64 + (h0 & 63);
  const unsigned tag = (unsigned)(ec + 1);
  unsigned long long q[4];
  for (;;) {
    bool ok = true;
#pragma unroll
    for (int i = 0; i < 4; ++i) {
      q[i] = ld64(kb + i);
      ok &= ((unsigned)(q[i] >> 32) == tag);
    }
    if (ok) break;
    __builtin_amdgcn_s_sleep(1);
  }
  *(float4*)(smem + KOFF + slot * 4096 + w * 256 + h0) =
      make_float4(__uint_as_float((unsigned)q[0]), __uint_as_float((unsigned)q[1]),
                  __uint_as_float((unsigned)q[2]), __uint_as_float((unsigned)q[3]));
}

// k-history read (thread-private slot)
#define KH(i) (*(const float4*)(smem + KOFF + (i) * 4096 + w * 256 + h0))

#define EVAL(SLOT, KS, TS)                                                     \
  do {                                                                         \
    eval_front(smem, kpk, bhr, blr, rg, sub, lane, w, fo, t, ec, ys, (TS),     \
               cr0, cz0, bn_, wtr, wtz, wtn, bhn, KS);                         \
    eval_poll(smem, kpk, rg, w, lane, h0, ec, SLOT);                           \
    ++ec;                                                                      \
  } while (0)

__global__ void __launch_bounds__(1024, 1)
ode_pk4(const float* __restrict__ x,
        const float* __restrict__ tp, int nt,
        const float* __restrict__ bp,
        const float* __restrict__ Wih,
        const float* __restrict__ bih,
        const float* __restrict__ bhh,
        const float* __restrict__ bl,
        const float* __restrict__ ws_f,
        unsigned long long* __restrict__ kpk,
        unsigned long long* __restrict__ ppk,
        float* __restrict__ out) {
  extern __shared__ float smem[];

  const int bid = blockIdx.x;
  const int rg = bid & 31;      // rows rg*16 .. rg*16+15
  const int sub = bid >> 5;     // h-slice [64*sub, 64*sub+64)
  const int t = threadIdx.x;
  const int lane = t & 63;
  const int w = t >> 6;         // wave 0..15 == owned row
  const int h0 = lane * 4;      // owned A-elements (row w, h0..h0+3)
  const int fo = ((h0 >> 5) * 64 + w + ((h0 >> 3) & 3) * 16) * 8 + (h0 & 7);

  const unsigned short* wbh = (const unsigned short*)ws_f;
  const unsigned short* wbl = ((const unsigned short*)ws_f) + 196608;
  const float* Wpt = ws_f + 196608;
  const float* Wlt = ws_f + 229376;

  const float t0 = tp[0];
  const float t1v = tp[nt - 1];

  // ---- B (this wave's n-tile, all 8 ksteps, hi+lo) -> 64 VGPRs, ONCE ----
  bf16x8s bhr[8], blr[8];
  if (w < 12) {
    const int ntg = (w >> 2) * 16 + sub * 4 + (w & 3);  // global n-tile
#pragma unroll
    for (int ks2 = 0; ks2 < 8; ++ks2) {
      bhr[ks2] = *(const bf16x8s*)(wbh + ((ntg * 8 + ks2) * 64 + lane) * 8);
      blr[ks2] = *(const bf16x8s*)(wbl + ((ntg * 8 + ks2) * 64 + lane) * 8);
    }
  } else {
#pragma unroll
    for (int ks2 = 0; ks2 < 8; ++ks2) {
      bhr[ks2] = bf16x8s{0, 0, 0, 0, 0, 0, 0, 0};
      blr[ks2] = bf16x8s{0, 0, 0, 0, 0, 0, 0, 0};
    }
  }

  // ---- per-thread nonlinearity consts for global h = sub*64 + (t&63) ----
  const int gh = sub * 64 + (t & 63);
  const float cr0 = bih[gh] + bhh[gh];
  const float cz0 = bih[256 + gh] + bhh[256 + gh];
  const float bn_ = bih[512 + gh];
  const float bhn = bhh[512 + gh];
  const float wtr = Wih[gh * 257 + 256];
  const float wtz = Wih[(256 + gh) * 257 + 256];
  const float wtn = Wih[(512 + gh) * 257 + 256];

  // ---- stage x (16 rows x 128) into frag area (aliased) ----
  for (int i = t; i < 2048; i += 1024)
    smem[i] = x[(rg * 16 + (i >> 7)) * 128 + (i & 127)];
  __syncthreads();

  // ---- h0 = x @ Wp.T + bp: owner elements (row w, h0..h0+3) ----
  // (bitwise-identical fmaf chain to rounds 2..7 for each element)
  float yb[4];
  {
    float acc[4] = {0.f, 0.f, 0.f, 0.f};
    for (int k = 0; k < 128; ++k) {
      const float xv0 = smem[w * 128 + k];
      const float4 wv4 = *(const float4*)(Wpt + k * 256 + h0);
      acc[0] = fmaf(xv0, wv4.x, acc[0]);
      acc[1] = fmaf(xv0, wv4.y, acc[1]);
      acc[2] = fmaf(xv0, wv4.z, acc[2]);
      acc[3] = fmaf(xv0, wv4.w, acc[3]);
    }
    const float4 bp4 = *(const float4*)(bp + h0);
    yb[0] = acc[0] + bp4.x; yb[1] = acc[1] + bp4.y;
    yb[2] = acc[2] + bp4.z; yb[3] = acc[3] + bp4.w;
  }
  // ---- h0 for this thread's SLICE element (row=t>>6, h=gh) ----
  float ybs;
  {
    const int row_s = t >> 6;
    float accs = 0.f;
    for (int k = 0; k < 128; ++k)
      accs = fmaf(smem[row_s * 128 + k], Wpt[k * 256 + gh], accs);
    ybs = accs + bp[gh];
  }
  __syncthreads();  // x-staging about to be overwritten by A-frags

  float tcur = t0;
  float dt = (t1v - t0) * 0.01f + 1e-8f;
  int ec = 0;

  float ys[4];
  float k1s, k2s, k3s, k4s, k5s, k6s, k7s;

#pragma unroll
  for (int c = 0; c < 4; ++c) ys[c] = yb[c];
  EVAL(0, k1s, t0);  // k1 -> slot 0; FSAL afterwards

  for (int step = 0; step < 64; ++step) {
    if (t1v - tcur <= 1e-6f) break;  // exact: ref freezes state once done
    const float dtc = fminf(dt, t1v - tcur);

    {
      const float4 K1 = KH(0);
#pragma unroll
      for (int c = 0; c < 4; ++c) ys[c] = fmaf(dtc * 0.2f, K1[c], yb[c]);
    }
    EVAL(1, k2s, tcur + dtc * 0.2f);

    {
      const float4 K1 = KH(0); const float4 K2 = KH(1);
#pragma unroll
      for (int c = 0; c < 4; ++c)
        ys[c] = fmaf(dtc, fmaf(F(9.0/40.0), K2[c], F(3.0/40.0) * K1[c]), yb[c]);
    }
    EVAL(2, k3s, tcur + dtc * 0.3f);

    {
      const float4 K1 = KH(0); const float4 K2 = KH(1); const float4 K3 = KH(2);
#pragma unroll
      for (int c = 0; c < 4; ++c) {
        float in_ = F(44.0/45.0) * K1[c];
        in_ = fmaf(F(-56.0/15.0), K2[c], in_);
        in_ = fmaf(F(32.0/9.0), K3[c], in_);
        ys[c] = fmaf(dtc, in_, yb[c]);
      }
    }
    EVAL(3, k4s, tcur + dtc * 0.8f);

    {
      const float4 K1 = KH(0); const float4 K2 = KH(1); const float4 K3 = KH(2);
      const float4 K4 = KH(3);
#pragma unroll
      for (int c = 0; c < 4; ++c) {
        float in_ = F(19372.0/6561.0) * K1[c];
        in_ = fmaf(F(-25360.0/2187.0), K2[c], in_);
        in_ = fmaf(F(64448.0/6561.0), K3[c], in_);
        in_ = fmaf(F(-212.0/729.0), K4[c], in_);
        ys[c] = fmaf(dtc, in_, yb[c]);
      }
    }
    EVAL(4, k5s, tcur + dtc * F(8.0/9.0));

    {
      const float4 K1 = KH(0); const float4 K2 = KH(1); const float4 K3 = KH(2);
      const float4 K4 = KH(3); const float4 K5 = KH(4);
#pragma unroll
      for (int c = 0; c < 4; ++c) {
        float in_ = F(9017.0/3168.0) * K1[c];
        in_ = fmaf(F(-355.0/33.0), K2[c], in_);
        in_ = fmaf(F(46732.0/5247.0), K3[c], in_);
        in_ = fmaf(F(49.0/176.0), K4[c], in_);
        in_ = fmaf(F(-5103.0/18656.0), K5[c], in_);
        ys[c] = fmaf(dtc, in_, yb[c]);
      }
    }
    EVAL(5, k6s, tcur + dtc);

    // y5 into ys, then k7 front; err partial published before k7 poll.
    {
      const float4 K1 = KH(0); const float4 K3 = KH(2); const float4 K4 = KH(3);
      const float4 K5 = KH(4); const float4 K6 = KH(5);
#pragma unroll
      for (int c = 0; c < 4; ++c) {
        float in_ = F(35.0/384.0) * K1[c];
        in_ = fmaf(F(500.0/1113.0), K3[c], in_);
        in_ = fmaf(F(125.0/192.0), K4[c], in_);
        in_ = fmaf(F(-2187.0/6784.0), K5[c], in_);
        in_ = fmaf(F(11.0/84.0), K6[c], in_);
        ys[c] = fmaf(dtc, in_, yb[c]);
      }
    }
    eval_front(smem, kpk, bhr, blr, rg, sub, lane, w, fo, t, ec, ys,
               tcur + dtc, cr0, cz0, bn_, wtr, wtz, wtn, bhn, k7s);

    // ---- slice y5 + err element (local; bitwise same chains) ----
    float y5s;
    {
      float in_ = F(35.0/384.0) * k1s;
      in_ = fmaf(F(500.0/1113.0), k3s, in_);
      in_ = fmaf(F(125.0/192.0), k4s, in_);
      in_ = fmaf(F(-2187.0/6784.0), k5s, in_);
      in_ = fmaf(F(11.0/84.0), k6s, in_);
      y5s = fmaf(dtc, in_, ybs);
    }
    double lsum;
    {
      float ev = F(71.0/57600.0) * k1s;
      ev = fmaf(F(-71.0/16695.0), k3s, ev);
      ev = fmaf(F(71.0/1920.0), k4s, ev);
      ev = fmaf(F(-17253.0/339200.0), k5s, ev);
      ev = fmaf(F(22.0/525.0), k6s, ev);
      ev = fmaf(F(-1.0/40.0), k7s, ev);
      ev *= dtc;
      const float sc = 1e-6f + 1e-5f * fmaxf(fabsf(ybs), fabsf(y5s));
      const float qq = ev / sc;
      lsum = (double)(qq * qq);
    }
    // block slice-partial: wave butterfly -> 16 wave sums -> t0 serial sum
    double v = lsum;
#pragma unroll
    for (int d = 1; d < 64; d <<= 1) v += __shfl_xor(v, d, 64);
    if (lane == 0) ((double*)(smem + REDF))[w] = v;
    __syncthreads();
    if (t == 0) {
      double s = ((double*)(smem + REDF))[0];
#pragma unroll
      for (int i = 1; i < 16; ++i) s += ((double*)(smem + REDF))[i];
      const unsigned long long bits =
          (unsigned long long)__double_as_longlong(s);
      const unsigned long long tg =
          ((unsigned long long)(unsigned)(step + 1)) << 32;
      unsigned long long* pb = ppk + ((size_t)((step & 1) * 32 + rg) * 4 + sub) * 2;
      pub64(pb + 0, tg | (unsigned)(bits & 0xffffffffull));
      pub64(pb + 1, tg | (unsigned)(bits >> 32));
    }
    // ---- poll k7 packets (overlapped with partial propagation) ----
    eval_poll(smem, kpk, rg, w, lane, h0, ec, 6);
    ++ec;
    __syncthreads();  // red[] reuse below

    // ---- poll all 128 slice partials; fixed-tree global sum ----
    double myp = 0.0;
    if (t < 128) {
      const int prg = t >> 2, psub = t & 3;
      const unsigned long long* pb =
          ppk + ((size_t)((step & 1) * 32 + prg) * 4 + psub) * 2;
      const unsigned tg = (unsigned)(step + 1);
      unsigned long long a, b;
      for (;;) {
        a = ld64(pb + 0);
        b = ld64(pb + 1);
        if (((unsigned)(a >> 32) == tg) && ((unsigned)(b >> 32) == tg)) break;
        __builtin_amdgcn_s_sleep(1);
      }
      myp = __longlong_as_double(
          (long long)(((unsigned long long)(unsigned)b << 32) |
                      (unsigned)(a & 0xffffffffull)));
    }
    double v3 = myp;
#pragma unroll
    for (int d = 1; d < 64; d <<= 1) v3 += __shfl_xor(v3, d, 64);
    if (lane == 0) ((double*)(smem + REDF))[w] = v3;
    __syncthreads();
    if (t == 0) {
      double s = ((double*)(smem + REDF))[0];
#pragma unroll
      for (int i = 1; i < 16; ++i) s += ((double*)(smem + REDF))[i];
      ((double*)(smem + SBF))[0] = s;
    }
    __syncthreads();
    const double sb = ((double*)(smem + SBF))[0];
    const float err_norm = sqrtf((float)(sb / 131072.0));
    const bool accept = (err_norm <= 1.0f);
    float factor = 0.9f * powf(err_norm + 1e-10f, -0.2f);
    factor = fminf(10.0f, fmaxf(0.2f, factor));
    if (accept) {
      tcur = tcur + dtc;
#pragma unroll
      for (int c = 0; c < 4; ++c) yb[c] = ys[c];  // ys == y5
      // FSAL: k_lds slot0 <- slot6 (thread-private 16B copy)
      *(float4*)(smem + KOFF + 0 * 4096 + w * 256 + h0) = KH(6);
      ybs = y5s; k1s = k7s;
    }
    dt = dtc * factor;
  }

  // ---- out = y @ Wl.T + bl (sub==0 blocks only) ----
  __syncthreads();
#pragma unroll
  for (int c = 0; c < 4; ++c) smem[w * 256 + h0 + c] = yb[c];
  __syncthreads();
  if (sub == 0) {
    const int orow = t >> 6, oc = t & 63;
    float acc = bl[oc];
    for (int k = 0; k < 256; ++k)
      acc = fmaf(smem[orow * 256 + k], Wlt[k * 64 + oc], acc);
    out[(rg * 16 + orow) * 64 + oc] = acc;
  }
}

extern "C" void kernel_launch(void* const* d_in, const int* in_sizes, int n_in,
                              void* d_out, int out_size, void* d_ws, size_t ws_size,
                              hipStream_t stream) {
  const float* x   = (const float*)d_in[0];
  const float* tp  = (const float*)d_in[1];
  const float* Wp  = (const float*)d_in[2];
  const float* bp  = (const float*)d_in[3];
  const float* Wih = (const float*)d_in[4];
  const float* bih = (const float*)d_in[5];
  const float* bhh = (const float*)d_in[7];
  const float* Wl  = (const float*)d_in[8];
  const float* bl  = (const float*)d_in[9];
  float* out = (float*)d_out;
  float* ws_f = (float*)d_ws;
  unsigned long long* kpk = (unsigned long long*)((char*)d_ws + 1048576);
  unsigned long long* ppk = (unsigned long long*)((char*)d_ws + 3145728);
  int nt = in_sizes[1];

  hipLaunchKernelGGL(prep_kernel, dim3(960), dim3(256), 0, stream, Wih, Wp, Wl, ws_f);
  // zero packet regions every launch: deterministic across graph replays
  hipMemsetAsync((char*)d_ws + 1048576, 0, 2101248, stream);

  const size_t shbytes = 143808;
  hipFuncSetAttribute((const void*)ode_pk4,
                      hipFuncAttributeMaxDynamicSharedMemorySize, (int)shbytes);

  void* args[] = { (void*)&x, (void*)&tp, (void*)&nt, (void*)&bp, (void*)&Wih,
                   (void*)&bih, (void*)&bhh, (void*)&bl, (void*)&ws_f,
                   (void*)&kpk, (void*)&ppk, (void*)&out };
  hipLaunchCooperativeKernel((void*)ode_pk4, dim3(128), dim3(1024), args,
                             shbytes, stream);
}

// Round 10
// 365.047 us; speedup vs baseline: 1.0987x; 1.0987x over previous
//
#include <hip/hip_runtime.h>
#include <math.h>

// ---------------------------------------------------------------------------
// Round 9: round-6 structure with ownership remap for coalesced exchange.
//  - 256 blocks x 512 threads. rg = bid&31 owns 16 rows; sub = bid>>5 owns
//    h-slice [32*sub,32*sub+32). B (hi+lo) in registers (waves 0..5).
//  - NEW ownership: thread (w,lane) owns row=lane&15, h0=w*32+(lane>>4)*8
//    (8 consecutive h). Derived properties:
//      * A-frag slot index = t*8+j  -> pack = two coalesced 16B LDS writes
//      * poll = ONE contiguous 64B line (8 u64 packets)
//      * wave w polls exactly ONE producer block (rg, sub=w)
//  - A contents / B / MFMA chain / nonlin / controller bitwise identical to
//    round 6 (passed, 300us, absmax 0.0078125) -> identical trajectory.
//  - Sleep-first polls (round-7 lesson: hot-spin floods the fabric).
//
// ws layout (bytes):
//   [0,393216)        Wb_hi  ushort[196608] B-frag-packed bf16 hi Wih[:,:256]
//   [393216,786432)   Wb_lo  ushort[196608] bf16 lo
//   [786432,917504)   Wpt    float[32768]
//   [917504,983040)   Wlt    float[16384]
//   [1048576,3145728) kpk    u64[2][32][8][16][32]  k packets (seq|bits)
//   [3145728,3153920) ppk    u64[2][32][8][2]       err-partial packets
// Dynamic LDS (floats):
//   [0,4096)  A-frags: yh bytes [0,8192) + yl bytes [8192,16384), XOR-swizzled
//             (alias: x-staging at init, y at end)
//   [4096,5696) g_lds[16][100] | [5696,5712) red double[8] | [5712) s_b double
// ---------------------------------------------------------------------------

typedef __attribute__((ext_vector_type(8))) short bf16x8s;
typedef __attribute__((ext_vector_type(8))) unsigned short u16x8;
typedef __attribute__((ext_vector_type(4))) float f32x4;

#define F(x) ((float)(x))
#define GLDS 4096
#define REDF 5696
#define SBF 5712
// byte-offset XOR swizzle within each 8KB A-frag region (write & read sides)
#define SWZ(b) ((b) ^ ((((b) >> 8) & 7) << 4))

static __device__ __forceinline__ unsigned short f2bf(float f) {
  unsigned u = __float_as_uint(f);
  unsigned r = (u + 0x7FFFu + ((u >> 16) & 1u)) >> 16;
  return (unsigned short)r;
}
static __device__ __forceinline__ float bf2f(unsigned short b) {
  return __uint_as_float(((unsigned)b) << 16);
}
static __device__ __forceinline__ float sigm(float x) {
  return 1.0f / (1.0f + __expf(-x));
}
static __device__ __forceinline__ float tanh_fast(float x) {
  float e = __expf(-2.0f * fabsf(x));
  float t = (1.0f - e) / (1.0f + e);
  return copysignf(t, x);
}
static __device__ __forceinline__ void pub64(unsigned long long* p,
                                             unsigned long long v) {
  __hip_atomic_store(p, v, __ATOMIC_RELAXED, __HIP_MEMORY_SCOPE_AGENT);
}
static __device__ __forceinline__ unsigned long long ld64(
    const unsigned long long* p) {
  return __hip_atomic_load(p, __ATOMIC_RELAXED, __HIP_MEMORY_SCOPE_AGENT);
}

__global__ void prep_kernel(const float* __restrict__ Wih,
                            const float* __restrict__ Wp,
                            const float* __restrict__ Wl,
                            float* __restrict__ ws) {
  int i = blockIdx.x * blockDim.x + threadIdx.x;
  if (i < 196608) {
    const int j = i & 7, l = (i >> 3) & 63, ks = (i >> 9) & 7, nt = i >> 12;
    const int c = nt * 16 + (l & 15);          // gate-output column
    const int k = ks * 32 + (l >> 4) * 8 + j;  // k index (same perm as A)
    const float f = Wih[c * 257 + k];
    unsigned short hi = f2bf(f);
    unsigned short lo = f2bf(f - bf2f(hi));
    ((unsigned short*)ws)[i] = hi;
    ((unsigned short*)ws)[196608 + i] = lo;
  } else if (i < 229376) {
    int ii = i - 196608; int hh = ii & 255, k = ii >> 8;
    ws[i] = Wp[hh * 128 + k];
  } else if (i < 245760) {
    int ii = i - 229376; int c = ii & 63, k = ii >> 6;
    ws[i] = Wl[c * 256 + k];
  }
}

// Front half of one f-eval: pack -> MFMA -> nonlin -> publish k packets.
// Returns this thread's slice-k value (row=t>>5, hl=t&31) in ks_out.
__device__ __forceinline__ void eval_front(
    float* __restrict__ smem, unsigned long long* __restrict__ kpk,
    const bf16x8s (&bhr)[8], const bf16x8s (&blr)[8],
    int rg, int sub, int lane, int w, int t, int ec,
    const float (&ys)[8], float ts_,
    float cr0, float cz0, float bn_, float wtr, float wtz, float wtn,
    float bhn, float& ks_out) {
  // ---- pack ys -> A-frags (bf16 hi/lo): slot index = t*8+j (coalesced) ----
  u16x8 hv, lv;
#pragma unroll
  for (int c = 0; c < 8; ++c) {
    const unsigned short hh = f2bf(ys[c]);
    hv[c] = hh;
    lv[c] = f2bf(ys[c] - bf2f(hh));
  }
  char* yB = (char*)smem;
  *(u16x8*)(yB + SWZ(16 * t)) = hv;
  *(u16x8*)(yB + 8192 + SWZ(16 * t)) = lv;
  __syncthreads();

  // ---- MFMA: waves 0..5, B in registers, single-acc chain (== round 6) ----
  if (w < 6) {
    f32x4 ac = {0.f, 0.f, 0.f, 0.f};
#pragma unroll
    for (int ks2 = 0; ks2 < 8; ++ks2) {
      const int rb = SWZ(16 * (ks2 * 64 + lane));
      const bf16x8s ah = *(const bf16x8s*)(yB + rb);
      const bf16x8s al = *(const bf16x8s*)(yB + 8192 + rb);
      ac = __builtin_amdgcn_mfma_f32_16x16x32_bf16(al, bhr[ks2], ac, 0, 0, 0);
      ac = __builtin_amdgcn_mfma_f32_16x16x32_bf16(ah, blr[ks2], ac, 0, 0, 0);
      ac = __builtin_amdgcn_mfma_f32_16x16x32_bf16(ah, bhr[ks2], ac, 0, 0, 0);
    }
    // C: col=lane&15, row=(lane>>4)*4+j -> g_lds[row][w*16+col] (stride 100)
    const int gcol = w * 16 + (lane & 15);
    const int gr0 = (lane >> 4) * 4;
#pragma unroll
    for (int j = 0; j < 4; ++j) smem[GLDS + (gr0 + j) * 100 + gcol] = ac[j];
  }
  __syncthreads();

  // ---- GRU nonlinearity for (row=t>>5, hl=t&31); publish packet ----
  {
    const int row = t >> 5, hl = t & 31;
    const float gR = smem[GLDS + row * 100 + hl];
    const float gZ = smem[GLDS + row * 100 + 32 + hl];
    const float gN = smem[GLDS + row * 100 + 64 + hl];
    const float rv = sigm(gR + cr0 + ts_ * wtr);
    const float zv = sigm(gZ + cz0 + ts_ * wtz);
    const float nv = tanh_fast(gN + bn_ + ts_ * wtn + rv * bhn);
    const float kv = (1.0f - zv) * nv;
    ks_out = kv;
    pub64(kpk + ((size_t)((ec & 1) * 32 + rg) * 8 + sub) * 512 + row * 32 + hl,
          ((unsigned long long)(unsigned)(ec + 1) << 32) | __float_as_uint(kv));
  }
}

// Poll own 8 k packets: ONE contiguous 64B line from producer (rg, sub=w).
// (row = lane&15, h = w*32 + (lane>>4)*8 + 0..7)
__device__ __forceinline__ void eval_poll(
    const unsigned long long* __restrict__ kpk,
    int rg, int w, int lane, int ec, float (&kout)[8]) {
  const unsigned long long* kb =
      kpk + ((size_t)((ec & 1) * 32 + rg) * 8 + w) * 512 +
      (lane & 15) * 32 + (lane >> 4) * 8;
  const unsigned tag = (unsigned)(ec + 1);
  unsigned long long q[8];
  for (;;) {
    bool ok = true;
#pragma unroll
    for (int i = 0; i < 8; ++i) {
      q[i] = ld64(kb + i);
      ok &= ((unsigned)(q[i] >> 32) == tag);
    }
    if (ok) break;
    __builtin_amdgcn_s_sleep(1);
  }
#pragma unroll
  for (int i = 0; i < 8; ++i) kout[i] = __uint_as_float((unsigned)q[i]);
}

#define EVAL(KOUT, KS, TS)                                                     \
  do {                                                                         \
    eval_front(smem, kpk, bhr, blr, rg, sub, lane, w, t, ec, ys, (TS),         \
               cr0, cz0, bn_, wtr, wtz, wtn, bhn, KS);                         \
    eval_poll(kpk, rg, w, lane, ec, KOUT);                                     \
    ++ec;                                                                      \
  } while (0)

__global__ void __launch_bounds__(512)
ode_pk(const float* __restrict__ x,
       const float* __restrict__ tp, int nt,
       const float* __restrict__ bp,
       const float* __restrict__ Wih,
       const float* __restrict__ bih,
       const float* __restrict__ bhh,
       const float* __restrict__ bl,
       const float* __restrict__ ws_f,
       unsigned long long* __restrict__ kpk,
       unsigned long long* __restrict__ ppk,
       float* __restrict__ out) {
  extern __shared__ float smem[];

  const int bid = blockIdx.x;
  const int rg = bid & 31;      // rows rg*16 .. rg*16+15
  const int sub = bid >> 5;     // h-slice [32*sub, 32*sub+32)
  const int t = threadIdx.x;
  const int lane = t & 63;
  const int w = t >> 6;         // wave 0..7
  const int orow = lane & 15;           // owned row
  const int oh0 = w * 32 + (lane >> 4) * 8;  // owned h-range (8 consecutive)

  const unsigned short* wbh = (const unsigned short*)ws_f;
  const unsigned short* wbl = ((const unsigned short*)ws_f) + 196608;
  const float* Wpt = ws_f + 196608;
  const float* Wlt = ws_f + 229376;

  const float t0 = tp[0];
  const float t1v = tp[nt - 1];

  // ---- B (this wave's n-tile, all 8 ksteps, hi+lo) -> regs, ONCE ----
  bf16x8s bhr[8], blr[8];
  if (w < 6) {
    const int ntg = (w >> 1) * 16 + sub * 2 + (w & 1);  // global n-tile
#pragma unroll
    for (int ks2 = 0; ks2 < 8; ++ks2) {
      bhr[ks2] = *(const bf16x8s*)(wbh + ((ntg * 8 + ks2) * 64 + lane) * 8);
      blr[ks2] = *(const bf16x8s*)(wbl + ((ntg * 8 + ks2) * 64 + lane) * 8);
    }
  } else {
#pragma unroll
    for (int ks2 = 0; ks2 < 8; ++ks2) {
      bhr[ks2] = bf16x8s{0, 0, 0, 0, 0, 0, 0, 0};
      blr[ks2] = bf16x8s{0, 0, 0, 0, 0, 0, 0, 0};
    }
  }

  // ---- per-thread nonlinearity consts for global h = sub*32 + (t&31) ----
  const int gh = sub * 32 + (t & 31);
  const float cr0 = bih[gh] + bhh[gh];
  const float cz0 = bih[256 + gh] + bhh[256 + gh];
  const float bn_ = bih[512 + gh];
  const float bhn = bhh[512 + gh];
  const float wtr = Wih[gh * 257 + 256];
  const float wtz = Wih[(256 + gh) * 257 + 256];
  const float wtn = Wih[(512 + gh) * 257 + 256];

  // ---- stage x (16 rows x 128) into frag area (aliased) ----
  for (int i = t; i < 2048; i += 512)
    smem[i] = x[(rg * 16 + (i >> 7)) * 128 + (i & 127)];
  __syncthreads();

  // ---- h0 = x @ Wp.T + bp: owner elements (orow, oh0..oh0+7) ----
  // (per-element fmaf chain identical to rounds 2..6)
  float yb[8];
  {
    float acc[8] = {0.f, 0.f, 0.f, 0.f, 0.f, 0.f, 0.f, 0.f};
    for (int k = 0; k < 128; ++k) {
      const float xv = smem[orow * 128 + k];
      const float4 wa = *(const float4*)(Wpt + k * 256 + oh0);
      const float4 wb = *(const float4*)(Wpt + k * 256 + oh0 + 4);
      acc[0] = fmaf(xv, wa.x, acc[0]);
      acc[1] = fmaf(xv, wa.y, acc[1]);
      acc[2] = fmaf(xv, wa.z, acc[2]);
      acc[3] = fmaf(xv, wa.w, acc[3]);
      acc[4] = fmaf(xv, wb.x, acc[4]);
      acc[5] = fmaf(xv, wb.y, acc[5]);
      acc[6] = fmaf(xv, wb.z, acc[6]);
      acc[7] = fmaf(xv, wb.w, acc[7]);
    }
    const float4 ba = *(const float4*)(bp + oh0);
    const float4 bb = *(const float4*)(bp + oh0 + 4);
    yb[0] = acc[0] + ba.x; yb[1] = acc[1] + ba.y;
    yb[2] = acc[2] + ba.z; yb[3] = acc[3] + ba.w;
    yb[4] = acc[4] + bb.x; yb[5] = acc[5] + bb.y;
    yb[6] = acc[6] + bb.z; yb[7] = acc[7] + bb.w;
  }
  // ---- h0 for this thread's SLICE element (row=t>>5, h=gh): bitwise same
  //      scalar chain as the owner's computation of that element ----
  float ybs;
  {
    const int row_s = t >> 5;
    float accs = 0.f;
    for (int k = 0; k < 128; ++k)
      accs = fmaf(smem[row_s * 128 + k], Wpt[k * 256 + gh], accs);
    ybs = accs + bp[gh];
  }
  __syncthreads();  // x-staging about to be overwritten by A-frags

  float tcur = t0;
  float dt = (t1v - t0) * 0.01f + 1e-8f;
  int ec = 0;

  float k1v[8], k2v[8], k3v[8], k4v[8], k5v[8], k6v[8], k7v[8];
  float ys[8];
  float k1s, k2s, k3s, k4s, k5s, k6s, k7s;

#pragma unroll
  for (int c = 0; c < 8; ++c) ys[c] = yb[c];
  EVAL(k1v, k1s, t0);  // k1; FSAL afterwards

  for (int step = 0; step < 64; ++step) {
    if (t1v - tcur <= 1e-6f) break;  // exact: ref freezes state once done
    const float dtc = fminf(dt, t1v - tcur);

#pragma unroll
    for (int c = 0; c < 8; ++c) ys[c] = fmaf(dtc * 0.2f, k1v[c], yb[c]);
    EVAL(k2v, k2s, tcur + dtc * 0.2f);

#pragma unroll
    for (int c = 0; c < 8; ++c)
      ys[c] = fmaf(dtc, fmaf(F(9.0/40.0), k2v[c], F(3.0/40.0) * k1v[c]), yb[c]);
    EVAL(k3v, k3s, tcur + dtc * 0.3f);

#pragma unroll
    for (int c = 0; c < 8; ++c) {
      float in_ = F(44.0/45.0) * k1v[c];
      in_ = fmaf(F(-56.0/15.0), k2v[c], in_);
      in_ = fmaf(F(32.0/9.0), k3v[c], in_);
      ys[c] = fmaf(dtc, in_, yb[c]);
    }
    EVAL(k4v, k4s, tcur + dtc * 0.8f);

#pragma unroll
    for (int c = 0; c < 8; ++c) {
      float in_ = F(19372.0/6561.0) * k1v[c];
      in_ = fmaf(F(-25360.0/2187.0), k2v[c], in_);
      in_ = fmaf(F(64448.0/6561.0), k3v[c], in_);
      in_ = fmaf(F(-212.0/729.0), k4v[c], in_);
      ys[c] = fmaf(dtc, in_, yb[c]);
    }
    EVAL(k5v, k5s, tcur + dtc * F(8.0/9.0));

#pragma unroll
    for (int c = 0; c < 8; ++c) {
      float in_ = F(9017.0/3168.0) * k1v[c];
      in_ = fmaf(F(-355.0/33.0), k2v[c], in_);
      in_ = fmaf(F(46732.0/5247.0), k3v[c], in_);
      in_ = fmaf(F(49.0/176.0), k4v[c], in_);
      in_ = fmaf(F(-5103.0/18656.0), k5v[c], in_);
      ys[c] = fmaf(dtc, in_, yb[c]);
    }
    EVAL(k6v, k6s, tcur + dtc);

    // y5 into ys, then k7 = f(t+dt, y5) -- front only; err partial is
    // published from LOCAL slice history BEFORE polling k7 (overlap).
#pragma unroll
    for (int c = 0; c < 8; ++c) {
      float in_ = F(35.0/384.0) * k1v[c];
      in_ = fmaf(F(500.0/1113.0), k3v[c], in_);
      in_ = fmaf(F(125.0/192.0), k4v[c], in_);
      in_ = fmaf(F(-2187.0/6784.0), k5v[c], in_);
      in_ = fmaf(F(11.0/84.0), k6v[c], in_);
      ys[c] = fmaf(dtc, in_, yb[c]);
    }
    eval_front(smem, kpk, bhr, blr, rg, sub, lane, w, t, ec, ys,
               tcur + dtc, cr0, cz0, bn_, wtr, wtz, wtn, bhn, k7s);

    // ---- slice y5 + err element (local; bitwise same chains) ----
    float y5s;
    {
      float in_ = F(35.0/384.0) * k1s;
      in_ = fmaf(F(500.0/1113.0), k3s, in_);
      in_ = fmaf(F(125.0/192.0), k4s, in_);
      in_ = fmaf(F(-2187.0/6784.0), k5s, in_);
      in_ = fmaf(F(11.0/84.0), k6s, in_);
      y5s = fmaf(dtc, in_, ybs);
    }
    double lsum;
    {
      float ev = F(71.0/57600.0) * k1s;
      ev = fmaf(F(-71.0/16695.0), k3s, ev);
      ev = fmaf(F(71.0/1920.0), k4s, ev);
      ev = fmaf(F(-17253.0/339200.0), k5s, ev);
      ev = fmaf(F(22.0/525.0), k6s, ev);
      ev = fmaf(F(-1.0/40.0), k7s, ev);
      ev *= dtc;
      const float sc = 1e-6f + 1e-5f * fmaxf(fabsf(ybs), fabsf(y5s));
      const float qq = ev / sc;
      lsum = (double)(qq * qq);
    }
    // block slice-partial: wave butterfly -> 8 wave sums -> t0 serial sum
    double v = lsum;
#pragma unroll
    for (int d = 1; d < 64; d <<= 1) v += __shfl_xor(v, d, 64);
    if (lane == 0) ((double*)(smem + REDF))[w] = v;
    __syncthreads();
    if (t == 0) {
      double s = ((double*)(smem + REDF))[0];
#pragma unroll
      for (int i = 1; i < 8; ++i) s += ((double*)(smem + REDF))[i];
      const unsigned long long bits =
          (unsigned long long)__double_as_longlong(s);
      const unsigned long long tg =
          ((unsigned long long)(unsigned)(step + 1)) << 32;
      unsigned long long* pb = ppk + ((size_t)((step & 1) * 32 + rg) * 8 + sub) * 2;
      pub64(pb + 0, tg | (unsigned)(bits & 0xffffffffull));
      pub64(pb + 1, tg | (unsigned)(bits >> 32));
    }
    // ---- poll k7 packets (overlapped with partial propagation) ----
    eval_poll(kpk, rg, w, lane, ec, k7v);
    ++ec;
    __syncthreads();  // red[] reuse below

    // ---- poll all 256 slice partials; fixed-tree global sum ----
    double myp = 0.0;
    if (t < 256) {
      const int prg = t >> 3, psub = t & 7;
      const unsigned long long* pb =
          ppk + ((size_t)((step & 1) * 32 + prg) * 8 + psub) * 2;
      const unsigned tg = (unsigned)(step + 1);
      unsigned long long a, b;
      for (;;) {
        a = ld64(pb + 0);
        b = ld64(pb + 1);
        if (((unsigned)(a >> 32) == tg) && ((unsigned)(b >> 32) == tg)) break;
        __builtin_amdgcn_s_sleep(1);
      }
      myp = __longlong_as_double(
          (long long)(((unsigned long long)(unsigned)b << 32) |
                      (unsigned)(a & 0xffffffffull)));
    }
    double v3 = myp;
#pragma unroll
    for (int d = 1; d < 64; d <<= 1) v3 += __shfl_xor(v3, d, 64);
    if (lane == 0) ((double*)(smem + REDF))[w] = v3;
    __syncthreads();
    if (t == 0) {
      double s = ((double*)(smem + REDF))[0];
#pragma unroll
      for (int i = 1; i < 8; ++i) s += ((double*)(smem + REDF))[i];
      ((double*)(smem + SBF))[0] = s;
    }
    __syncthreads();
    const double sb = ((double*)(smem + SBF))[0];
    const float err_norm = sqrtf((float)(sb / 131072.0));
    const bool accept = (err_norm <= 1.0f);
    float factor = 0.9f * powf(err_norm + 1e-10f, -0.2f);
    factor = fminf(10.0f, fmaxf(0.2f, factor));
    if (accept) {
      tcur = tcur + dtc;
#pragma unroll
      for (int c = 0; c < 8; ++c) { yb[c] = ys[c]; k1v[c] = k7v[c]; }  // FSAL
      ybs = y5s; k1s = k7s;
    }
    dt = dtc * factor;
  }

  // ---- out = y @ Wl.T + bl (sub==0 blocks only) ----
  __syncthreads();
#pragma unroll
  for (int c = 0; c < 8; ++c) smem[orow * 256 + oh0 + c] = yb[c];
  __syncthreads();
  if (sub == 0) {
    const int oc = t & 63;
#pragma unroll
    for (int rr = 0; rr < 2; ++rr) {
      const int orw = (t >> 6) + rr * 8;
      float acc = bl[oc];
      for (int k = 0; k < 256; ++k)
        acc = fmaf(smem[orw * 256 + k], Wlt[k * 64 + oc], acc);
      out[(rg * 16 + orw) * 64 + oc] = acc;
    }
  }
}

extern "C" void kernel_launch(void* const* d_in, const int* in_sizes, int n_in,
                              void* d_out, int out_size, void* d_ws, size_t ws_size,
                              hipStream_t stream) {
  const float* x   = (const float*)d_in[0];
  const float* tp  = (const float*)d_in[1];
  const float* Wp  = (const float*)d_in[2];
  const float* bp  = (const float*)d_in[3];
  const float* Wih = (const float*)d_in[4];
  const float* bih = (const float*)d_in[5];
  const float* bhh = (const float*)d_in[7];
  const float* Wl  = (const float*)d_in[8];
  const float* bl  = (const float*)d_in[9];
  float* out = (float*)d_out;
  float* ws_f = (float*)d_ws;
  unsigned long long* kpk = (unsigned long long*)((char*)d_ws + 1048576);
  unsigned long long* ppk = (unsigned long long*)((char*)d_ws + 3145728);
  int nt = in_sizes[1];

  hipLaunchKernelGGL(prep_kernel, dim3(960), dim3(256), 0, stream, Wih, Wp, Wl, ws_f);
  // zero packet regions every launch: deterministic across graph replays
  hipMemsetAsync((char*)d_ws + 1048576, 0, 2105344, stream);

  const size_t shbytes = 23040;
  hipFuncSetAttribute((const void*)ode_pk,
                      hipFuncAttributeMaxDynamicSharedMemorySize, (int)shbytes);

  void* args[] = { (void*)&x, (void*)&tp, (void*)&nt, (void*)&bp, (void*)&Wih,
                   (void*)&bih, (void*)&bhh, (void*)&bl, (void*)&ws_f,
                   (void*)&kpk, (void*)&ppk, (void*)&out };
  hipLaunchCooperativeKernel((void*)ode_pk, dim3(256), dim3(512), args,
                             shbytes, stream);
}

// Round 11
// 299.642 us; speedup vs baseline: 1.3385x; 1.2183x over previous
//
#include <hip/hip_runtime.h>
#include <math.h>

// ---------------------------------------------------------------------------
// Round 10 = Round 6 verbatim (best measured: 300us, absmax 0.0078125).
// r7 (hot-spin), r8 (4-way split + LDS k-history), r9 (ownership remap) each
// regressed through a different mechanism (fabric flood / bank conflicts /
// write-phase conflicts). r6 is the measured local optimum; residual cost is
// the structural per-eval cross-block k-broadcast (1 L2 RTT x 151 evals) and
// ~25 sequential controller broadcasts, with all pipes <15% loaded.
//
//  - 256 blocks x 512 threads. rg = bid&31 owns 16 rows; sub = bid>>5 owns
//    h-slice [32*sub,32*sub+32). B (hi+lo) in registers (waves 0..5).
//  - Per eval: pack A-frags (XOR-swizzled LDS) -> 24 MFMA -> g_lds ->
//    nonlinearity -> publish k as (seq|bits) u64 packets -> poll own 8
//    packets until seq matches. ONE remote leg per eval; no flags/grid.sync.
//  - Per step: each block publishes its OWN slice err partial overlapping the
//    k7 packet latency; all blocks poll 256 partial-pairs, fixed-tree reduce.
//  - Packet regions zeroed via hipMemsetAsync each launch (graph-safe).
//
// ws layout (bytes):
//   [0,393216)        Wb_hi  ushort[196608] B-frag-packed bf16 hi Wih[:,:256]
//   [393216,786432)   Wb_lo  ushort[196608] bf16 lo
//   [786432,917504)   Wpt    float[32768]
//   [917504,983040)   Wlt    float[16384]
//   [1048576,3145728) kpk    u64[2][32][8][16][32]  k packets (seq|bits)
//   [3145728,3153920) ppk    u64[2][32][8][2]       err-partial packets
// Dynamic LDS (floats):
//   [0,4096)  A-frags: yh bytes [0,8192) + yl bytes [8192,16384), XOR-swizzled
//             (alias: x-staging at init, y at end)
//   [4096,5696) g_lds[16][100] | [5696,5712) red double[8] | [5712) s_b double
// ---------------------------------------------------------------------------

typedef __attribute__((ext_vector_type(8))) short bf16x8s;
typedef __attribute__((ext_vector_type(4))) float f32x4;

#define F(x) ((float)(x))
#define GLDS 4096
#define REDF 5696
#define SBF 5712
// byte-offset XOR swizzle within each 8KB A-frag region (write & read sides)
#define SWZ(b) ((b) ^ ((((b) >> 8) & 7) << 4))

static __device__ __forceinline__ unsigned short f2bf(float f) {
  unsigned u = __float_as_uint(f);
  unsigned r = (u + 0x7FFFu + ((u >> 16) & 1u)) >> 16;
  return (unsigned short)r;
}
static __device__ __forceinline__ float bf2f(unsigned short b) {
  return __uint_as_float(((unsigned)b) << 16);
}
static __device__ __forceinline__ float sigm(float x) {
  return 1.0f / (1.0f + __expf(-x));
}
static __device__ __forceinline__ float tanh_fast(float x) {
  float e = __expf(-2.0f * fabsf(x));
  float t = (1.0f - e) / (1.0f + e);
  return copysignf(t, x);
}
static __device__ __forceinline__ void pub64(unsigned long long* p,
                                             unsigned long long v) {
  __hip_atomic_store(p, v, __ATOMIC_RELAXED, __HIP_MEMORY_SCOPE_AGENT);
}
static __device__ __forceinline__ unsigned long long ld64(
    const unsigned long long* p) {
  return __hip_atomic_load(p, __ATOMIC_RELAXED, __HIP_MEMORY_SCOPE_AGENT);
}

__global__ void prep_kernel(const float* __restrict__ Wih,
                            const float* __restrict__ Wp,
                            const float* __restrict__ Wl,
                            float* __restrict__ ws) {
  int i = blockIdx.x * blockDim.x + threadIdx.x;
  if (i < 196608) {
    const int j = i & 7, l = (i >> 3) & 63, ks = (i >> 9) & 7, nt = i >> 12;
    const int c = nt * 16 + (l & 15);          // gate-output column
    const int k = ks * 32 + (l >> 4) * 8 + j;  // k index (same perm as A)
    const float f = Wih[c * 257 + k];
    unsigned short hi = f2bf(f);
    unsigned short lo = f2bf(f - bf2f(hi));
    ((unsigned short*)ws)[i] = hi;
    ((unsigned short*)ws)[196608 + i] = lo;
  } else if (i < 229376) {
    int ii = i - 196608; int hh = ii & 255, k = ii >> 8;
    ws[i] = Wp[hh * 128 + k];
  } else if (i < 245760) {
    int ii = i - 229376; int c = ii & 63, k = ii >> 6;
    ws[i] = Wl[c * 256 + k];
  }
}

// Front half of one f-eval: pack -> MFMA -> nonlin -> publish k packets.
// Returns this thread's slice-k value (row=t>>5, hl=t&31) in ks_out.
__device__ __forceinline__ void eval_front(
    float* __restrict__ smem, unsigned long long* __restrict__ kpk,
    const bf16x8s (&bhr)[8], const bf16x8s (&blr)[8],
    int rg, int sub, int lane, int w, int fo0, int fo1, int t, int ec,
    const float (&ys)[8], float ts_,
    float cr0, float cz0, float bn_, float wtr, float wtz, float wtn,
    float bhn, float& ks_out) {
  // ---- pack ys -> A-frags (bf16 hi/lo), swizzled locations ----
  unsigned short h_[8], l_[8];
#pragma unroll
  for (int c = 0; c < 8; ++c) {
    h_[c] = f2bf(ys[c]);
    l_[c] = f2bf(ys[c] - bf2f(h_[c]));
  }
  char* yB = (char*)smem;
  *(ushort4*)(yB + SWZ(2 * fo0)) = make_ushort4(h_[0], h_[1], h_[2], h_[3]);
  *(ushort4*)(yB + SWZ(2 * fo1)) = make_ushort4(h_[4], h_[5], h_[6], h_[7]);
  *(ushort4*)(yB + 8192 + SWZ(2 * fo0)) = make_ushort4(l_[0], l_[1], l_[2], l_[3]);
  *(ushort4*)(yB + 8192 + SWZ(2 * fo1)) = make_ushort4(l_[4], l_[5], l_[6], l_[7]);
  __syncthreads();

  // ---- MFMA: waves 0..5, B in registers, swizzled A reads ----
  if (w < 6) {
    f32x4 ac = {0.f, 0.f, 0.f, 0.f};
#pragma unroll
    for (int ks2 = 0; ks2 < 8; ++ks2) {
      const int rb = SWZ(16 * (ks2 * 64 + lane));
      const bf16x8s ah = *(const bf16x8s*)(yB + rb);
      const bf16x8s al = *(const bf16x8s*)(yB + 8192 + rb);
      ac = __builtin_amdgcn_mfma_f32_16x16x32_bf16(al, bhr[ks2], ac, 0, 0, 0);
      ac = __builtin_amdgcn_mfma_f32_16x16x32_bf16(ah, blr[ks2], ac, 0, 0, 0);
      ac = __builtin_amdgcn_mfma_f32_16x16x32_bf16(ah, bhr[ks2], ac, 0, 0, 0);
    }
    // C: col=lane&15, row=(lane>>4)*4+j -> g_lds[row][w*16+col] (stride 100)
    const int gcol = w * 16 + (lane & 15);
    const int gr0 = (lane >> 4) * 4;
#pragma unroll
    for (int j = 0; j < 4; ++j) smem[GLDS + (gr0 + j) * 100 + gcol] = ac[j];
  }
  __syncthreads();

  // ---- GRU nonlinearity for (row=t>>5, hl=t&31); publish packet ----
  {
    const int row = t >> 5, hl = t & 31;
    const float gR = smem[GLDS + row * 100 + hl];
    const float gZ = smem[GLDS + row * 100 + 32 + hl];
    const float gN = smem[GLDS + row * 100 + 64 + hl];
    const float rv = sigm(gR + cr0 + ts_ * wtr);
    const float zv = sigm(gZ + cz0 + ts_ * wtz);
    const float nv = tanh_fast(gN + bn_ + ts_ * wtn + rv * bhn);
    const float kv = (1.0f - zv) * nv;
    ks_out = kv;
    pub64(kpk + ((size_t)((ec & 1) * 32 + rg) * 8 + sub) * 512 + row * 32 + hl,
          ((unsigned long long)(unsigned)(ec + 1) << 32) | __float_as_uint(kv));
  }
}

// Poll own 8 k packets (rows w, w+8 at h0..h0+3) for this eval.
__device__ __forceinline__ void eval_poll(
    const unsigned long long* __restrict__ kpk,
    int rg, int w, int h0, int ec, float (&kout)[8]) {
  const int subsrc = h0 >> 5;
  const unsigned long long* kb =
      kpk + ((size_t)((ec & 1) * 32 + rg) * 8 + subsrc) * 512 + (h0 & 31);
  const unsigned tag = (unsigned)(ec + 1);
  unsigned long long q[8];
  for (;;) {
    bool ok = true;
#pragma unroll
    for (int i = 0; i < 8; ++i) {
      const int rr = (i >> 2) * 8 + w;  // rows w, w+8
      q[i] = ld64(kb + rr * 32 + (i & 3));
      ok &= ((unsigned)(q[i] >> 32) == tag);
    }
    if (ok) break;
    __builtin_amdgcn_s_sleep(1);
  }
#pragma unroll
  for (int i = 0; i < 8; ++i) kout[i] = __uint_as_float((unsigned)q[i]);
}

#define EVAL(KOUT, KS, TS)                                                     \
  do {                                                                         \
    eval_front(smem, kpk, bhr, blr, rg, sub, lane, w, fo0, fo1, t, ec, ys,     \
               (TS), cr0, cz0, bn_, wtr, wtz, wtn, bhn, KS);                   \
    eval_poll(kpk, rg, w, h0, ec, KOUT);                                       \
    ++ec;                                                                      \
  } while (0)

__global__ void __launch_bounds__(512)
ode_pk(const float* __restrict__ x,
       const float* __restrict__ tp, int nt,
       const float* __restrict__ bp,
       const float* __restrict__ Wih,
       const float* __restrict__ bih,
       const float* __restrict__ bhh,
       const float* __restrict__ bl,
       const float* __restrict__ ws_f,
       unsigned long long* __restrict__ kpk,
       unsigned long long* __restrict__ ppk,
       float* __restrict__ out) {
  extern __shared__ float smem[];

  const int bid = blockIdx.x;
  const int rg = bid & 31;      // rows rg*16 .. rg*16+15
  const int sub = bid >> 5;     // h-slice [32*sub, 32*sub+32)
  const int t = threadIdx.x;
  const int lane = t & 63;
  const int w = t >> 6;         // wave 0..7; thread owns rows {w, w+8}
  const int h0 = lane * 4;      // owned hidden indices h0..h0+3
  const int fo0 = ((h0 >> 5) * 64 + w + ((h0 >> 3) & 3) * 16) * 8 + (h0 & 7);
  const int fo1 = ((h0 >> 5) * 64 + (w + 8) + ((h0 >> 3) & 3) * 16) * 8 + (h0 & 7);

  const unsigned short* wbh = (const unsigned short*)ws_f;
  const unsigned short* wbl = ((const unsigned short*)ws_f) + 196608;
  const float* Wpt = ws_f + 196608;
  const float* Wlt = ws_f + 229376;

  const float t0 = tp[0];
  const float t1v = tp[nt - 1];

  // ---- B (this wave's n-tile, all 8 ksteps, hi+lo) -> regs, ONCE ----
  bf16x8s bhr[8], blr[8];
  if (w < 6) {
    const int ntg = (w >> 1) * 16 + sub * 2 + (w & 1);  // global n-tile
#pragma unroll
    for (int ks2 = 0; ks2 < 8; ++ks2) {
      bhr[ks2] = *(const bf16x8s*)(wbh + ((ntg * 8 + ks2) * 64 + lane) * 8);
      blr[ks2] = *(const bf16x8s*)(wbl + ((ntg * 8 + ks2) * 64 + lane) * 8);
    }
  } else {
#pragma unroll
    for (int ks2 = 0; ks2 < 8; ++ks2) {
      bhr[ks2] = bf16x8s{0, 0, 0, 0, 0, 0, 0, 0};
      blr[ks2] = bf16x8s{0, 0, 0, 0, 0, 0, 0, 0};
    }
  }

  // ---- per-thread nonlinearity consts for global h = sub*32 + (t&31) ----
  const int gh = sub * 32 + (t & 31);
  const float cr0 = bih[gh] + bhh[gh];
  const float cz0 = bih[256 + gh] + bhh[256 + gh];
  const float bn_ = bih[512 + gh];
  const float bhn = bhh[512 + gh];
  const float wtr = Wih[gh * 257 + 256];
  const float wtz = Wih[(256 + gh) * 257 + 256];
  const float wtn = Wih[(512 + gh) * 257 + 256];

  // ---- stage x (16 rows x 128) into frag area (aliased) ----
  for (int i = t; i < 2048; i += 512)
    smem[i] = x[(rg * 16 + (i >> 7)) * 128 + (i & 127)];
  __syncthreads();

  // ---- h0 = x @ Wp.T + bp: owner elements (rows w,w+8 x h0..h0+3) ----
  float yb[8];
  {
    float acc[8] = {0.f, 0.f, 0.f, 0.f, 0.f, 0.f, 0.f, 0.f};
    for (int k = 0; k < 128; ++k) {
      const float xv0 = smem[w * 128 + k];
      const float xv1 = smem[(w + 8) * 128 + k];
      const float4 wv4 = *(const float4*)(Wpt + k * 256 + h0);
      acc[0] = fmaf(xv0, wv4.x, acc[0]);
      acc[1] = fmaf(xv0, wv4.y, acc[1]);
      acc[2] = fmaf(xv0, wv4.z, acc[2]);
      acc[3] = fmaf(xv0, wv4.w, acc[3]);
      acc[4] = fmaf(xv1, wv4.x, acc[4]);
      acc[5] = fmaf(xv1, wv4.y, acc[5]);
      acc[6] = fmaf(xv1, wv4.z, acc[6]);
      acc[7] = fmaf(xv1, wv4.w, acc[7]);
    }
    const float4 bp4 = *(const float4*)(bp + h0);
    yb[0] = acc[0] + bp4.x; yb[1] = acc[1] + bp4.y;
    yb[2] = acc[2] + bp4.z; yb[3] = acc[3] + bp4.w;
    yb[4] = acc[4] + bp4.x; yb[5] = acc[5] + bp4.y;
    yb[6] = acc[6] + bp4.z; yb[7] = acc[7] + bp4.w;
  }
  // ---- h0 for this thread's SLICE element (row=t>>5, h=gh): bitwise same
  //      scalar chain as the owner's computation of that element ----
  float ybs;
  {
    const int row_s = t >> 5;
    float accs = 0.f;
    for (int k = 0; k < 128; ++k)
      accs = fmaf(smem[row_s * 128 + k], Wpt[k * 256 + gh], accs);
    ybs = accs + bp[gh];
  }
  __syncthreads();  // x-staging about to be overwritten by A-frags

  float tcur = t0;
  float dt = (t1v - t0) * 0.01f + 1e-8f;
  int ec = 0;

  float k1v[8], k2v[8], k3v[8], k4v[8], k5v[8], k6v[8], k7v[8];
  float ys[8];
  float k1s, k2s, k3s, k4s, k5s, k6s, k7s;

#pragma unroll
  for (int c = 0; c < 8; ++c) ys[c] = yb[c];
  EVAL(k1v, k1s, t0);  // k1; FSAL afterwards

  for (int step = 0; step < 64; ++step) {
    if (t1v - tcur <= 1e-6f) break;  // exact: ref freezes state once done
    const float dtc = fminf(dt, t1v - tcur);

#pragma unroll
    for (int c = 0; c < 8; ++c) ys[c] = fmaf(dtc * 0.2f, k1v[c], yb[c]);
    EVAL(k2v, k2s, tcur + dtc * 0.2f);

#pragma unroll
    for (int c = 0; c < 8; ++c)
      ys[c] = fmaf(dtc, fmaf(F(9.0/40.0), k2v[c], F(3.0/40.0) * k1v[c]), yb[c]);
    EVAL(k3v, k3s, tcur + dtc * 0.3f);

#pragma unroll
    for (int c = 0; c < 8; ++c) {
      float in_ = F(44.0/45.0) * k1v[c];
      in_ = fmaf(F(-56.0/15.0), k2v[c], in_);
      in_ = fmaf(F(32.0/9.0), k3v[c], in_);
      ys[c] = fmaf(dtc, in_, yb[c]);
    }
    EVAL(k4v, k4s, tcur + dtc * 0.8f);

#pragma unroll
    for (int c = 0; c < 8; ++c) {
      float in_ = F(19372.0/6561.0) * k1v[c];
      in_ = fmaf(F(-25360.0/2187.0), k2v[c], in_);
      in_ = fmaf(F(64448.0/6561.0), k3v[c], in_);
      in_ = fmaf(F(-212.0/729.0), k4v[c], in_);
      ys[c] = fmaf(dtc, in_, yb[c]);
    }
    EVAL(k5v, k5s, tcur + dtc * F(8.0/9.0));

#pragma unroll
    for (int c = 0; c < 8; ++c) {
      float in_ = F(9017.0/3168.0) * k1v[c];
      in_ = fmaf(F(-355.0/33.0), k2v[c], in_);
      in_ = fmaf(F(46732.0/5247.0), k3v[c], in_);
      in_ = fmaf(F(49.0/176.0), k4v[c], in_);
      in_ = fmaf(F(-5103.0/18656.0), k5v[c], in_);
      ys[c] = fmaf(dtc, in_, yb[c]);
    }
    EVAL(k6v, k6s, tcur + dtc);

    // y5 into ys, then k7 = f(t+dt, y5) -- front only; err partial is
    // published from LOCAL slice history BEFORE polling k7 (overlap).
#pragma unroll
    for (int c = 0; c < 8; ++c) {
      float in_ = F(35.0/384.0) * k1v[c];
      in_ = fmaf(F(500.0/1113.0), k3v[c], in_);
      in_ = fmaf(F(125.0/192.0), k4v[c], in_);
      in_ = fmaf(F(-2187.0/6784.0), k5v[c], in_);
      in_ = fmaf(F(11.0/84.0), k6v[c], in_);
      ys[c] = fmaf(dtc, in_, yb[c]);
    }
    eval_front(smem, kpk, bhr, blr, rg, sub, lane, w, fo0, fo1, t, ec, ys,
               tcur + dtc, cr0, cz0, bn_, wtr, wtz, wtn, bhn, k7s);

    // ---- slice y5 + err element (local; bitwise same chains) ----
    float y5s;
    {
      float in_ = F(35.0/384.0) * k1s;
      in_ = fmaf(F(500.0/1113.0), k3s, in_);
      in_ = fmaf(F(125.0/192.0), k4s, in_);
      in_ = fmaf(F(-2187.0/6784.0), k5s, in_);
      in_ = fmaf(F(11.0/84.0), k6s, in_);
      y5s = fmaf(dtc, in_, ybs);
    }
    double lsum;
    {
      float ev = F(71.0/57600.0) * k1s;
      ev = fmaf(F(-71.0/16695.0), k3s, ev);
      ev = fmaf(F(71.0/1920.0), k4s, ev);
      ev = fmaf(F(-17253.0/339200.0), k5s, ev);
      ev = fmaf(F(22.0/525.0), k6s, ev);
      ev = fmaf(F(-1.0/40.0), k7s, ev);
      ev *= dtc;
      const float sc = 1e-6f + 1e-5f * fmaxf(fabsf(ybs), fabsf(y5s));
      const float qq = ev / sc;
      lsum = (double)(qq * qq);
    }
    // block slice-partial: wave butterfly -> 8 wave sums -> t0 serial sum
    double v = lsum;
#pragma unroll
    for (int d = 1; d < 64; d <<= 1) v += __shfl_xor(v, d, 64);
    if (lane == 0) ((double*)(smem + REDF))[w] = v;
    __syncthreads();
    if (t == 0) {
      double s = ((double*)(smem + REDF))[0];
#pragma unroll
      for (int i = 1; i < 8; ++i) s += ((double*)(smem + REDF))[i];
      const unsigned long long bits =
          (unsigned long long)__double_as_longlong(s);
      const unsigned long long tg =
          ((unsigned long long)(unsigned)(step + 1)) << 32;
      unsigned long long* pb = ppk + ((size_t)((step & 1) * 32 + rg) * 8 + sub) * 2;
      pub64(pb + 0, tg | (unsigned)(bits & 0xffffffffull));
      pub64(pb + 1, tg | (unsigned)(bits >> 32));
    }
    // ---- poll k7 packets (overlapped with partial propagation) ----
    eval_poll(kpk, rg, w, h0, ec, k7v);
    ++ec;
    __syncthreads();  // red[] reuse below

    // ---- poll all 256 slice partials; fixed-tree global sum ----
    double myp = 0.0;
    if (t < 256) {
      const int prg = t >> 3, psub = t & 7;
      const unsigned long long* pb =
          ppk + ((size_t)((step & 1) * 32 + prg) * 8 + psub) * 2;
      const unsigned tg = (unsigned)(step + 1);
      unsigned long long a, b;
      for (;;) {
        a = ld64(pb + 0);
        b = ld64(pb + 1);
        if (((unsigned)(a >> 32) == tg) && ((unsigned)(b >> 32) == tg)) break;
        __builtin_amdgcn_s_sleep(1);
      }
      myp = __longlong_as_double(
          (long long)(((unsigned long long)(unsigned)b << 32) |
                      (unsigned)(a & 0xffffffffull)));
    }
    double v3 = myp;
#pragma unroll
    for (int d = 1; d < 64; d <<= 1) v3 += __shfl_xor(v3, d, 64);
    if (lane == 0) ((double*)(smem + REDF))[w] = v3;
    __syncthreads();
    if (t == 0) {
      double s = ((double*)(smem + REDF))[0];
#pragma unroll
      for (int i = 1; i < 8; ++i) s += ((double*)(smem + REDF))[i];
      ((double*)(smem + SBF))[0] = s;
    }
    __syncthreads();
    const double sb = ((double*)(smem + SBF))[0];
    const float err_norm = sqrtf((float)(sb / 131072.0));
    const bool accept = (err_norm <= 1.0f);
    float factor = 0.9f * powf(err_norm + 1e-10f, -0.2f);
    factor = fminf(10.0f, fmaxf(0.2f, factor));
    if (accept) {
      tcur = tcur + dtc;
#pragma unroll
      for (int c = 0; c < 8; ++c) { yb[c] = ys[c]; k1v[c] = k7v[c]; }  // FSAL
      ybs = y5s; k1s = k7s;
    }
    dt = dtc * factor;
  }

  // ---- out = y @ Wl.T + bl (sub==0 blocks only) ----
  __syncthreads();
#pragma unroll
  for (int c = 0; c < 4; ++c) {
    smem[w * 256 + h0 + c] = yb[c];
    smem[(w + 8) * 256 + h0 + c] = yb[4 + c];
  }
  __syncthreads();
  if (sub == 0) {
    const int oc = t & 63;
#pragma unroll
    for (int rr = 0; rr < 2; ++rr) {
      const int orow = (t >> 6) + rr * 8;
      float acc = bl[oc];
      for (int k = 0; k < 256; ++k)
        acc = fmaf(smem[orow * 256 + k], Wlt[k * 64 + oc], acc);
      out[(rg * 16 + orow) * 64 + oc] = acc;
    }
  }
}

extern "C" void kernel_launch(void* const* d_in, const int* in_sizes, int n_in,
                              void* d_out, int out_size, void* d_ws, size_t ws_size,
                              hipStream_t stream) {
  const float* x   = (const float*)d_in[0];
  const float* tp  = (const float*)d_in[1];
  const float* Wp  = (const float*)d_in[2];
  const float* bp  = (const float*)d_in[3];
  const float* Wih = (const float*)d_in[4];
  const float* bih = (const float*)d_in[5];
  const float* bhh = (const float*)d_in[7];
  const float* Wl  = (const float*)d_in[8];
  const float* bl  = (const float*)d_in[9];
  float* out = (float*)d_out;
  float* ws_f = (float*)d_ws;
  unsigned long long* kpk = (unsigned long long*)((char*)d_ws + 1048576);
  unsigned long long* ppk = (unsigned long long*)((char*)d_ws + 3145728);
  int nt = in_sizes[1];

  hipLaunchKernelGGL(prep_kernel, dim3(960), dim3(256), 0, stream, Wih, Wp, Wl, ws_f);
  // zero packet regions every launch: deterministic across graph replays
  hipMemsetAsync((char*)d_ws + 1048576, 0, 2105344, stream);

  const size_t shbytes = 23040;
  hipFuncSetAttribute((const void*)ode_pk,
                      hipFuncAttributeMaxDynamicSharedMemorySize, (int)shbytes);

  void* args[] = { (void*)&x, (void*)&tp, (void*)&nt, (void*)&bp, (void*)&Wih,
                   (void*)&bih, (void*)&bhh, (void*)&bl, (void*)&ws_f,
                   (void*)&kpk, (void*)&ppk, (void*)&out };
  hipLaunchCooperativeKernel((void*)ode_pk, dim3(256), dim3(512), args,
                             shbytes, stream);
}